// Round 1
// baseline (1140.229 us; speedup 1.0000x reference)
//
#include <hip/hip_runtime.h>
#include <stdint.h>

typedef unsigned short u16;
typedef __bf16 bf16x8 __attribute__((ext_vector_type(8)));
typedef float f32x4 __attribute__((ext_vector_type(4)));

__device__ __forceinline__ u16 f2bf(float f) {
  union { float f; unsigned u; } v; v.f = f;
  return (u16)((v.u + 0x7FFFu + ((v.u >> 16) & 1u)) >> 16);
}

// ---------------- weight fp32 -> bf16 ----------------
__global__ __launch_bounds__(256) void cvt_weights(
    const float* __restrict__ wq, const float* __restrict__ wp,
    u16* __restrict__ oq, u16* __restrict__ op) {
  int i = blockIdx.x * 256 + threadIdx.x;
  if (i < 1536 * 512) oq[i] = f2bf(wq[i]);
  if (i < 512 * 512)  op[i] = f2bf(wp[i]);
}

// ---------------- group norm ----------------
// One block per (b, g): 16 channels * 4096 = 65536 contiguous floats.
__global__ __launch_bounds__(256) void gn_stats(const float* __restrict__ x,
                                                float* __restrict__ stats) {
  int bg = blockIdx.x;  // 0..127
  const float* p = x + (size_t)bg * 65536;
  float s = 0.f, sq = 0.f;
  for (int i = threadIdx.x * 4; i < 65536; i += 1024) {
    float4 v = *(const float4*)(p + i);
    s += v.x + v.y + v.z + v.w;
    sq += v.x * v.x + v.y * v.y + v.z * v.z + v.w * v.w;
  }
  int lane = threadIdx.x & 63, w = threadIdx.x >> 6;
  for (int off = 32; off; off >>= 1) {
    s += __shfl_down(s, off);
    sq += __shfl_down(sq, off);
  }
  __shared__ float ls[4], lq[4];
  if (lane == 0) { ls[w] = s; lq[w] = sq; }
  __syncthreads();
  if (threadIdx.x == 0) {
    float S = ls[0] + ls[1] + ls[2] + ls[3];
    float Q = lq[0] + lq[1] + lq[2] + lq[3];
    float mean = S * (1.f / 65536.f);
    float var = Q * (1.f / 65536.f) - mean * mean;
    stats[bg * 2] = mean;
    stats[bg * 2 + 1] = rsqrtf(var + 1e-6f);
  }
}

__global__ __launch_bounds__(256) void gn_norm(const float* __restrict__ x,
    const float* __restrict__ stats, const float* __restrict__ gamma,
    const float* __restrict__ beta, u16* __restrict__ xn) {
  size_t i = ((size_t)blockIdx.x * 256 + threadIdx.x) * 4;  // 4 elems/thread
  int c = (int)((i >> 12) & 511);
  int bg = (int)(i >> 16);
  float mean = stats[bg * 2], rstd = stats[bg * 2 + 1];
  float a = gamma[c] * rstd;
  float b2 = beta[c] - mean * a;
  float4 v = *(const float4*)(x + i);
  ushort4 o;
  o.x = f2bf(v.x * a + b2); o.y = f2bf(v.y * a + b2);
  o.z = f2bf(v.z * a + b2); o.w = f2bf(v.w * a + b2);
  *(ushort4*)(xn + i) = o;
}

// ---------------- generic 64x64-tile bf16 MFMA GEMM ----------------
// A_mfma[m][k] = A_KC ? A[m*lda+k] : A[k*lda+m]
// B_mfma[k][n] = B_KC ? B[n*ldb+k] : B[k*ldb+n]
// EPI: 0 = qkv (bias; *scale for m<1024; bf16 out)
//      1 = fp32 out (scores)
//      2 = bf16 out (PV)
//      3 = proj (bias + residual; fp32 out)
template<int A_KC, int B_KC, int EPI>
__global__ __launch_bounds__(256) void gemm_mfma(
    const u16* __restrict__ A, const u16* __restrict__ B, int lda, int ldb,
    const float* __restrict__ bias, const float* __restrict__ resid,
    float scale, float* __restrict__ outF, u16* __restrict__ outB,
    int ldo, int K) {
  __shared__ __align__(16) u16 Al[64][40];  // [m][k], +8 pad
  __shared__ __align__(16) u16 Bl[64][40];  // [n][k]
  const int t = threadIdx.x;
  const int m0 = blockIdx.y * 64, n0 = blockIdx.x * 64;
  const int wave = t >> 6, lane = t & 63;
  const int wm = wave >> 1, wn = wave & 1;
  const int quad = lane >> 4, li = lane & 15;

  f32x4 zero = {0.f, 0.f, 0.f, 0.f};
  f32x4 acc[2][2] = {{zero, zero}, {zero, zero}};

  for (int kt = 0; kt < K; kt += 32) {
    __syncthreads();
    if (A_KC) {
      int row = t >> 2, ch = t & 3;
      uint4 v = *(const uint4*)(A + (size_t)(m0 + row) * lda + kt + ch * 8);
      *(uint4*)&Al[row][ch * 8] = v;
    } else {
      int kk = t >> 3, mch = t & 7;
      uint4 v = *(const uint4*)(A + (size_t)(kt + kk) * lda + m0 + mch * 8);
      u16 e[8]; __builtin_memcpy(e, &v, 16);
      #pragma unroll
      for (int j = 0; j < 8; ++j) Al[mch * 8 + j][kk] = e[j];
    }
    if (B_KC) {
      int row = t >> 2, ch = t & 3;
      uint4 v = *(const uint4*)(B + (size_t)(n0 + row) * ldb + kt + ch * 8);
      *(uint4*)&Bl[row][ch * 8] = v;
    } else {
      int kk = t >> 3, nch = t & 7;
      uint4 v = *(const uint4*)(B + (size_t)(kt + kk) * ldb + n0 + nch * 8);
      u16 e[8]; __builtin_memcpy(e, &v, 16);
      #pragma unroll
      for (int j = 0; j < 8; ++j) Bl[nch * 8 + j][kk] = e[j];
    }
    __syncthreads();
    bf16x8 af[2], bfr[2];
    #pragma unroll
    for (int tm = 0; tm < 2; ++tm)
      af[tm] = *(const bf16x8*)&Al[wm * 32 + tm * 16 + li][quad * 8];
    #pragma unroll
    for (int tn = 0; tn < 2; ++tn)
      bfr[tn] = *(const bf16x8*)&Bl[wn * 32 + tn * 16 + li][quad * 8];
    #pragma unroll
    for (int tm = 0; tm < 2; ++tm)
      #pragma unroll
      for (int tn = 0; tn < 2; ++tn)
        acc[tm][tn] = __builtin_amdgcn_mfma_f32_16x16x32_bf16(
            af[tm], bfr[tn], acc[tm][tn], 0, 0, 0);
  }

  #pragma unroll
  for (int tm = 0; tm < 2; ++tm)
    #pragma unroll
    for (int tn = 0; tn < 2; ++tn)
      #pragma unroll
      for (int r = 0; r < 4; ++r) {
        int m = m0 + wm * 32 + tm * 16 + quad * 4 + r;
        int n = n0 + wn * 32 + tn * 16 + li;
        float v = acc[tm][tn][r];
        if (EPI == 0) {
          v += bias[m];
          if (m < 1024) v *= scale;
          outB[(size_t)m * ldo + n] = f2bf(v);
        } else if (EPI == 1) {
          outF[(size_t)m * ldo + n] = v;
        } else if (EPI == 2) {
          outB[(size_t)m * ldo + n] = f2bf(v);
        } else {
          v += bias[m] + resid[(size_t)m * ldo + n];
          outF[(size_t)m * ldo + n] = v;
        }
      }
}

// ---------------- row softmax (4096 fp32 -> 4096 bf16) ----------------
__global__ __launch_bounds__(256) void softmax_rows(const float* __restrict__ S,
                                                    u16* __restrict__ P) {
  int row = blockIdx.x;
  const float4* src = (const float4*)(S + (size_t)row * 4096);
  int t = threadIdx.x;
  float4 v[4];
  float m = -3.4e38f;
  #pragma unroll
  for (int i = 0; i < 4; ++i) {
    v[i] = src[t + i * 256];
    m = fmaxf(m, fmaxf(fmaxf(v[i].x, v[i].y), fmaxf(v[i].z, v[i].w)));
  }
  int lane = t & 63, w = t >> 6;
  for (int off = 32; off; off >>= 1) m = fmaxf(m, __shfl_down(m, off));
  __shared__ float red[4];
  if (lane == 0) red[w] = m;
  __syncthreads();
  m = fmaxf(fmaxf(red[0], red[1]), fmaxf(red[2], red[3]));
  __syncthreads();
  float s = 0.f;
  #pragma unroll
  for (int i = 0; i < 4; ++i) {
    v[i].x = __expf(v[i].x - m); v[i].y = __expf(v[i].y - m);
    v[i].z = __expf(v[i].z - m); v[i].w = __expf(v[i].w - m);
    s += v[i].x + v[i].y + v[i].z + v[i].w;
  }
  for (int off = 32; off; off >>= 1) s += __shfl_down(s, off);
  if (lane == 0) red[w] = s;
  __syncthreads();
  s = red[0] + red[1] + red[2] + red[3];
  float inv = 1.f / s;
  ushort4* dst = (ushort4*)(P + (size_t)row * 4096);
  #pragma unroll
  for (int i = 0; i < 4; ++i) {
    ushort4 o;
    o.x = f2bf(v[i].x * inv); o.y = f2bf(v[i].y * inv);
    o.z = f2bf(v[i].z * inv); o.w = f2bf(v[i].w * inv);
    dst[t + i * 256] = o;
  }
}

extern "C" void kernel_launch(void* const* d_in, const int* in_sizes, int n_in,
                              void* d_out, int out_size, void* d_ws, size_t ws_size,
                              hipStream_t stream) {
  (void)in_sizes; (void)n_in; (void)out_size; (void)ws_size;
  const float* x      = (const float*)d_in[0];
  const float* gamma  = (const float*)d_in[1];
  const float* beta   = (const float*)d_in[2];
  const float* w_qkv  = (const float*)d_in[3];
  const float* b_qkv  = (const float*)d_in[4];
  const float* w_proj = (const float*)d_in[5];
  const float* b_proj = (const float*)d_in[6];
  float* out = (float*)d_out;

  const int C = 512, N = 4096;
  const float scale = 0.21022410381342863f;  // 512^-0.25

  // ws layout (needs ~136.3 MB)
  char* ws = (char*)d_ws;
  size_t off = 0;
  auto alloc = [&](size_t bytes) -> char* {
    char* p = ws + off; off += (bytes + 255) & ~(size_t)255; return p;
  };
  u16*   wq_bf = (u16*)alloc((size_t)1536 * 512 * 2);
  u16*   wp_bf = (u16*)alloc((size_t)512 * 512 * 2);
  float* stats = (float*)alloc(128 * 2 * 4);
  u16*   xn    = (u16*)alloc((size_t)4 * C * N * 2);
  u16*   qkv   = (u16*)alloc((size_t)1536 * N * 2);   // per-batch
  float* S     = (float*)alloc((size_t)N * N * 4);    // per-batch
  u16*   P     = (u16*)alloc((size_t)N * N * 2);      // per-batch
  u16*   ao    = (u16*)alloc((size_t)N * C * 2);      // per-batch O[i][c]

  cvt_weights<<<3072, 256, 0, stream>>>(w_qkv, w_proj, wq_bf, wp_bf);
  gn_stats<<<128, 256, 0, stream>>>(x, stats);
  gn_norm<<<8192, 256, 0, stream>>>(x, stats, gamma, beta, xn);

  for (int b = 0; b < 4; ++b) {
    const u16* xb = xn + (size_t)b * C * N;
    const float* xres = x + (size_t)b * C * N;
    // QKV: qkv[o][n] = sum_c wq[o][c] * xn[c][n]  (+bias, q/k * scale)
    gemm_mfma<1, 0, 0><<<dim3(64, 24), 256, 0, stream>>>(
        wq_bf, xb, 512, 4096, b_qkv, nullptr, scale, nullptr, qkv, 4096, 512);
    // S[i][j] = sum_c q[c][i] * k[c][j]
    gemm_mfma<0, 0, 1><<<dim3(64, 64), 256, 0, stream>>>(
        qkv, qkv + (size_t)512 * 4096, 4096, 4096, nullptr, nullptr, 0.f,
        S, nullptr, 4096, 512);
    softmax_rows<<<4096, 256, 0, stream>>>(S, P);
    // O[i][c] = sum_j P[i][j] * v[c][j]
    gemm_mfma<1, 1, 2><<<dim3(8, 64), 256, 0, stream>>>(
        P, qkv + (size_t)1024 * 4096, 4096, 4096, nullptr, nullptr, 0.f,
        nullptr, ao, 512, 4096);
    // out[o][n] = sum_c wp[o][c] * O[n][c] + b_proj[o] + x[o][n]
    gemm_mfma<1, 1, 3><<<dim3(64, 8), 256, 0, stream>>>(
        wp_bf, ao, 512, 512, b_proj, xres, 0.f,
        out + (size_t)b * C * N, nullptr, 4096, 512);
  }
}

// Round 2
// 804.541 us; speedup vs baseline: 1.4172x; 1.4172x over previous
//
#include <hip/hip_runtime.h>
#include <stdint.h>

typedef unsigned short u16;
typedef __bf16 bf16x8 __attribute__((ext_vector_type(8)));
typedef float f32x4 __attribute__((ext_vector_type(4)));

__device__ __forceinline__ u16 f2bf(float f) {
  union { float f; unsigned u; } v; v.f = f;
  return (u16)((v.u + 0x7FFFu + ((v.u >> 16) & 1u)) >> 16);
}

// async 16B global -> LDS (wave-uniform LDS base; HW writes base + lane*16)
__device__ __forceinline__ void gld_lds16(const u16* g, u16* l) {
  uint32_t lo = (uint32_t)(uintptr_t)l;           // low 32 bits == LDS offset
  lo = __builtin_amdgcn_readfirstlane(lo);
  auto* lp = (__attribute__((address_space(3))) uint32_t*)(uintptr_t)lo;
  auto* gp = (const __attribute__((address_space(1))) uint32_t*)(uintptr_t)g;
  __builtin_amdgcn_global_load_lds(gp, lp, 16, 0, 0);
}

// ---------------- weight fp32 -> bf16 ----------------
__global__ __launch_bounds__(256) void cvt_weights(
    const float* __restrict__ wq, const float* __restrict__ wp,
    u16* __restrict__ oq, u16* __restrict__ op) {
  int i = blockIdx.x * 256 + threadIdx.x;
  if (i < 1536 * 512) oq[i] = f2bf(wq[i]);
  if (i < 512 * 512)  op[i] = f2bf(wp[i]);
}

// ---------------- group norm stats ----------------
__global__ __launch_bounds__(256) void gn_stats(const float* __restrict__ x,
                                                float* __restrict__ stats) {
  int bg = blockIdx.x;  // 0..127
  const float* p = x + (size_t)bg * 65536;
  float s = 0.f, sq = 0.f;
  for (int i = threadIdx.x * 4; i < 65536; i += 1024) {
    float4 v = *(const float4*)(p + i);
    s += v.x + v.y + v.z + v.w;
    sq += v.x * v.x + v.y * v.y + v.z * v.z + v.w * v.w;
  }
  int lane = threadIdx.x & 63, w = threadIdx.x >> 6;
  for (int off = 32; off; off >>= 1) {
    s += __shfl_down(s, off);
    sq += __shfl_down(sq, off);
  }
  __shared__ float ls[4], lq[4];
  if (lane == 0) { ls[w] = s; lq[w] = sq; }
  __syncthreads();
  if (threadIdx.x == 0) {
    float S = ls[0] + ls[1] + ls[2] + ls[3];
    float Q = lq[0] + lq[1] + lq[2] + lq[3];
    float mean = S * (1.f / 65536.f);
    float var = Q * (1.f / 65536.f) - mean * mean;
    stats[bg * 2] = mean;
    stats[bg * 2 + 1] = rsqrtf(var + 1e-6f);
  }
}

// ---------------- group norm + transpose: x[b][c][n] -> xnT[b][n][c] bf16 ----
__global__ __launch_bounds__(256) void gn_norm_t(const float* __restrict__ x,
    const float* __restrict__ stats, const float* __restrict__ gamma,
    const float* __restrict__ beta, u16* __restrict__ xnT) {
  __shared__ u16 tile[64][72];
  int b = blockIdx.z;
  int c0 = blockIdx.y * 64, n0 = blockIdx.x * 64;
  int t = threadIdx.x;
  int cl = t >> 2, ng = (t & 3) * 16;
  int c = c0 + cl;
  float mean = stats[(b * 32 + (c >> 4)) * 2];
  float rstd = stats[(b * 32 + (c >> 4)) * 2 + 1];
  float a = gamma[c] * rstd;
  float b2 = beta[c] - mean * a;
  const float* src = x + ((size_t)b * 512 + c) * 4096 + n0 + ng;
  u16 e[16];
  #pragma unroll
  for (int q = 0; q < 4; ++q) {
    float4 v = *(const float4*)(src + q * 4);
    e[q * 4 + 0] = f2bf(v.x * a + b2);
    e[q * 4 + 1] = f2bf(v.y * a + b2);
    e[q * 4 + 2] = f2bf(v.z * a + b2);
    e[q * 4 + 3] = f2bf(v.w * a + b2);
  }
  #pragma unroll
  for (int j = 0; j < 16; ++j) tile[ng + j][cl] = e[j];
  __syncthreads();
  int nl = t >> 2, cg = (t & 3) * 16;
  uint4 w0 = *(const uint4*)&tile[nl][cg];
  uint4 w1 = *(const uint4*)&tile[nl][cg + 8];
  u16* dst = xnT + ((size_t)b * 4096 + n0 + nl) * 512 + c0 + cg;
  *(uint4*)dst = w0;
  *(uint4*)(dst + 8) = w1;
}

// ---------------- u16 tiled transpose: out[c][r] = in[r][c] ----------------
__global__ __launch_bounds__(256) void transpose16(const u16* __restrict__ in,
    u16* __restrict__ out, int ld_in, int ld_out) {
  __shared__ u16 tile[64][72];
  int t = threadIdx.x;
  int r0 = blockIdx.y * 64, c0 = blockIdx.x * 64;
  int rl = t >> 2, cg = (t & 3) * 16;
  const u16* src = in + (size_t)(r0 + rl) * ld_in + c0 + cg;
  uint4 v0 = *(const uint4*)src;
  uint4 v1 = *(const uint4*)(src + 8);
  u16 e[16];
  __builtin_memcpy(e, &v0, 16);
  __builtin_memcpy(e + 8, &v1, 16);
  #pragma unroll
  for (int j = 0; j < 16; ++j) tile[cg + j][rl] = e[j];
  __syncthreads();
  int cl = t >> 2, rg = (t & 3) * 16;
  uint4 w0 = *(const uint4*)&tile[cl][rg];
  uint4 w1 = *(const uint4*)&tile[cl][rg + 8];
  u16* dst = out + (size_t)(c0 + cl) * ld_out + r0 + rg;
  *(uint4*)dst = w0;
  *(uint4*)(dst + 8) = w1;
}

// ---------------- unified NT GEMM: C[m][n] = sum_k A[m*lda+k]*B[n*ldb+k] ----
// 128x128 tile, BK=32, global_load_lds (no-pad LDS), 4 waves * 4x4 accs.
// EPI: 0 = qkv (+bias, *scale for m<1024, bf16 out)
//      1 = fp32 out (scores)
//      2 = bf16 out (PV)
//      3 = proj (+bias +residual, fp32 out)
template<int EPI>
__global__ __launch_bounds__(256) void gemm_nt(
    const u16* __restrict__ A, const u16* __restrict__ B,
    int lda, int ldb, int K,
    const float* __restrict__ bias, const float* __restrict__ resid,
    float scale, float* __restrict__ outF, u16* __restrict__ outB, int ldo) {
  __shared__ __align__(16) u16 Al[128 * 32];
  __shared__ __align__(16) u16 Bl[128 * 32];
  const int t = threadIdx.x;
  const int wave = t >> 6, lane = t & 63;
  const int wm = wave >> 1, wn = wave & 1;
  const int quad = lane >> 4, li = lane & 15;
  const int m0 = blockIdx.y * 128, n0 = blockIdx.x * 128;

  // staging: wave w, round r covers row-block rb = w + 4r (16 rows x 64B)
  const int srow = lane >> 2;         // 0..15 within row-block
  const int scol = (lane & 3) * 8;    // u16 col offset (16B chunks)
  const u16* gA[2];
  const u16* gB[2];
  u16* lA[2];
  u16* lB[2];
  #pragma unroll
  for (int r = 0; r < 2; ++r) {
    int rb = wave + 4 * r;
    gA[r] = A + (size_t)(m0 + rb * 16 + srow) * lda + scol;
    gB[r] = B + (size_t)(n0 + rb * 16 + srow) * ldb + scol;
    lA[r] = &Al[rb * 512];
    lB[r] = &Bl[rb * 512];
  }

  f32x4 zero = {0.f, 0.f, 0.f, 0.f};
  f32x4 acc[4][4];
  #pragma unroll
  for (int i = 0; i < 4; ++i)
    #pragma unroll
    for (int j = 0; j < 4; ++j) acc[i][j] = zero;

  for (int kt = 0; kt < K; kt += 32) {
    __syncthreads();
    #pragma unroll
    for (int r = 0; r < 2; ++r) {
      gld_lds16(gA[r] + kt, lA[r]);
      gld_lds16(gB[r] + kt, lB[r]);
    }
    __syncthreads();
    bf16x8 af[4], bf[4];
    #pragma unroll
    for (int i = 0; i < 4; ++i) {
      af[i] = *(const bf16x8*)&Al[(wm * 64 + i * 16 + li) * 32 + quad * 8];
      bf[i] = *(const bf16x8*)&Bl[(wn * 64 + i * 16 + li) * 32 + quad * 8];
    }
    #pragma unroll
    for (int i = 0; i < 4; ++i)
      #pragma unroll
      for (int j = 0; j < 4; ++j)
        acc[i][j] = __builtin_amdgcn_mfma_f32_16x16x32_bf16(
            af[i], bf[j], acc[i][j], 0, 0, 0);
  }

  #pragma unroll
  for (int i = 0; i < 4; ++i)
    #pragma unroll
    for (int j = 0; j < 4; ++j) {
      int mB = m0 + wm * 64 + i * 16 + quad * 4;
      int n = n0 + wn * 64 + j * 16 + li;
      #pragma unroll
      for (int r = 0; r < 4; ++r) {
        int m = mB + r;
        float v = acc[i][j][r];
        if (EPI == 0) {
          v += bias[m];
          if (m < 1024) v *= scale;
          outB[(size_t)m * ldo + n] = f2bf(v);
        } else if (EPI == 1) {
          outF[(size_t)m * ldo + n] = v;
        } else if (EPI == 2) {
          outB[(size_t)m * ldo + n] = f2bf(v);
        } else {
          v += bias[m] + resid[(size_t)m * ldo + n];
          outF[(size_t)m * ldo + n] = v;
        }
      }
    }
}

// ---------------- row softmax (4096 fp32 -> 4096 bf16) ----------------
__global__ __launch_bounds__(256) void softmax_rows(const float* __restrict__ S,
                                                    u16* __restrict__ P) {
  int row = blockIdx.x;
  const float4* src = (const float4*)(S + (size_t)row * 4096);
  int t = threadIdx.x;
  float4 v[4];
  float m = -3.4e38f;
  #pragma unroll
  for (int i = 0; i < 4; ++i) {
    v[i] = src[t + i * 256];
    m = fmaxf(m, fmaxf(fmaxf(v[i].x, v[i].y), fmaxf(v[i].z, v[i].w)));
  }
  int lane = t & 63, w = t >> 6;
  for (int off = 32; off; off >>= 1) m = fmaxf(m, __shfl_down(m, off));
  __shared__ float red[4];
  if (lane == 0) red[w] = m;
  __syncthreads();
  m = fmaxf(fmaxf(red[0], red[1]), fmaxf(red[2], red[3]));
  __syncthreads();
  float s = 0.f;
  #pragma unroll
  for (int i = 0; i < 4; ++i) {
    v[i].x = __expf(v[i].x - m); v[i].y = __expf(v[i].y - m);
    v[i].z = __expf(v[i].z - m); v[i].w = __expf(v[i].w - m);
    s += v[i].x + v[i].y + v[i].z + v[i].w;
  }
  for (int off = 32; off; off >>= 1) s += __shfl_down(s, off);
  if (lane == 0) red[w] = s;
  __syncthreads();
  s = red[0] + red[1] + red[2] + red[3];
  float inv = 1.f / s;
  ushort4* dst = (ushort4*)(P + (size_t)row * 4096);
  #pragma unroll
  for (int i = 0; i < 4; ++i) {
    ushort4 o;
    o.x = f2bf(v[i].x * inv); o.y = f2bf(v[i].y * inv);
    o.z = f2bf(v[i].z * inv); o.w = f2bf(v[i].w * inv);
    dst[t + i * 256] = o;
  }
}

extern "C" void kernel_launch(void* const* d_in, const int* in_sizes, int n_in,
                              void* d_out, int out_size, void* d_ws, size_t ws_size,
                              hipStream_t stream) {
  (void)in_sizes; (void)n_in; (void)out_size; (void)ws_size;
  const float* x      = (const float*)d_in[0];
  const float* gamma  = (const float*)d_in[1];
  const float* beta   = (const float*)d_in[2];
  const float* w_qkv  = (const float*)d_in[3];
  const float* b_qkv  = (const float*)d_in[4];
  const float* w_proj = (const float*)d_in[5];
  const float* b_proj = (const float*)d_in[6];
  float* out = (float*)d_out;

  const int C = 512, N = 4096;
  const float scale = 0.21022410381342863f;  // 512^-0.25

  char* ws = (char*)d_ws;
  size_t off = 0;
  auto alloc = [&](size_t bytes) -> char* {
    char* p = ws + off; off += (bytes + 255) & ~(size_t)255; return p;
  };
  u16*   wq_bf = (u16*)alloc((size_t)1536 * 512 * 2);
  u16*   wp_bf = (u16*)alloc((size_t)512 * 512 * 2);
  float* stats = (float*)alloc(128 * 2 * 4);
  u16*   xnT   = (u16*)alloc((size_t)4 * N * C * 2);  // [b][n][c]
  u16*   qkv   = (u16*)alloc((size_t)1536 * N * 2);   // per-batch [o][n]
  float* S     = (float*)alloc((size_t)N * N * 4);    // per-batch
  u16*   P     = (u16*)alloc((size_t)N * N * 2);      // per-batch
  u16*   ao    = (u16*)alloc((size_t)N * C * 2);      // per-batch O[i][c]
  u16*   qkT   = P;  // alias: qkT dead before softmax writes P

  cvt_weights<<<3072, 256, 0, stream>>>(w_qkv, w_proj, wq_bf, wp_bf);
  gn_stats<<<128, 256, 0, stream>>>(x, stats);
  gn_norm_t<<<dim3(64, 8, 4), 256, 0, stream>>>(x, stats, gamma, beta, xnT);

  for (int b = 0; b < 4; ++b) {
    const u16* xbT = xnT + (size_t)b * N * C;
    const float* xres = x + (size_t)b * C * N;
    // QKV: qkv[o][n] = sum_c wq[o][c]*xnT[n][c]  (+bias, q/k*scale)
    gemm_nt<0><<<dim3(32, 12), 256, 0, stream>>>(
        wq_bf, xbT, 512, 512, 512, b_qkv, nullptr, scale, nullptr, qkv, 4096);
    // transpose q,k: qkv[0:1024][4096] -> qkT[4096][1024]
    transpose16<<<dim3(64, 16), 256, 0, stream>>>(qkv, qkT, 4096, 1024);
    // S[i][j] = sum_c qkT[i][c]*qkT[j][512+c]
    gemm_nt<1><<<dim3(32, 32), 256, 0, stream>>>(
        qkT, qkT + 512, 1024, 1024, 512, nullptr, nullptr, 0.f, S, nullptr, 4096);
    softmax_rows<<<4096, 256, 0, stream>>>(S, P);
    // ao[i][c] = sum_j P[i][j]*v[c][j]
    gemm_nt<2><<<dim3(4, 32), 256, 0, stream>>>(
        P, qkv + (size_t)1024 * 4096, 4096, 4096, 4096, nullptr, nullptr, 0.f,
        nullptr, ao, 512);
    // out[o][n] = sum_c wp[o][c]*ao[n][c] + b_proj[o] + x[o][n]
    gemm_nt<3><<<dim3(32, 4), 256, 0, stream>>>(
        wp_bf, ao, 512, 512, 512, b_proj, xres, 0.f,
        out + (size_t)b * C * N, nullptr, 4096);
  }
}

// Round 3
// 672.477 us; speedup vs baseline: 1.6956x; 1.1964x over previous
//
#include <hip/hip_runtime.h>
#include <stdint.h>

typedef unsigned short u16;
typedef __bf16 bf16x8 __attribute__((ext_vector_type(8)));
typedef float f32x4 __attribute__((ext_vector_type(4)));

__device__ __forceinline__ u16 f2bf(float f) {
  union { float f; unsigned u; } v; v.f = f;
  return (u16)((v.u + 0x7FFFu + ((v.u >> 16) & 1u)) >> 16);
}

// async 16B global -> LDS (wave-uniform LDS base; HW writes base + lane*16)
__device__ __forceinline__ void gld_lds16(const u16* g, u16* l) {
  uint32_t lo = (uint32_t)(uintptr_t)l;
  lo = __builtin_amdgcn_readfirstlane(lo);
  auto* lp = (__attribute__((address_space(3))) uint32_t*)(uintptr_t)lo;
  auto* gp = (const __attribute__((address_space(1))) uint32_t*)(uintptr_t)g;
  __builtin_amdgcn_global_load_lds(gp, lp, 16, 0, 0);
}

// ---------------- weight fp32 -> bf16 ----------------
__global__ __launch_bounds__(256) void cvt_weights(
    const float* __restrict__ wq, const float* __restrict__ wp,
    u16* __restrict__ oq, u16* __restrict__ op) {
  int i = blockIdx.x * 256 + threadIdx.x;
  if (i < 1536 * 512) oq[i] = f2bf(wq[i]);
  if (i < 512 * 512)  op[i] = f2bf(wp[i]);
}

// ---------------- group norm stats ----------------
__global__ __launch_bounds__(256) void gn_stats(const float* __restrict__ x,
                                                float* __restrict__ stats) {
  int bg = blockIdx.x;  // 0..127
  const float* p = x + (size_t)bg * 65536;
  float s = 0.f, sq = 0.f;
  for (int i = threadIdx.x * 4; i < 65536; i += 1024) {
    float4 v = *(const float4*)(p + i);
    s += v.x + v.y + v.z + v.w;
    sq += v.x * v.x + v.y * v.y + v.z * v.z + v.w * v.w;
  }
  int lane = threadIdx.x & 63, w = threadIdx.x >> 6;
  for (int off = 32; off; off >>= 1) {
    s += __shfl_down(s, off);
    sq += __shfl_down(sq, off);
  }
  __shared__ float ls[4], lq[4];
  if (lane == 0) { ls[w] = s; lq[w] = sq; }
  __syncthreads();
  if (threadIdx.x == 0) {
    float S = ls[0] + ls[1] + ls[2] + ls[3];
    float Q = lq[0] + lq[1] + lq[2] + lq[3];
    float mean = S * (1.f / 65536.f);
    float var = Q * (1.f / 65536.f) - mean * mean;
    stats[bg * 2] = mean;
    stats[bg * 2 + 1] = rsqrtf(var + 1e-6f);
  }
}

// ---------------- group norm + transpose: x[b][c][n] -> xnT[b][n][c] bf16 ----
__global__ __launch_bounds__(256) void gn_norm_t(const float* __restrict__ x,
    const float* __restrict__ stats, const float* __restrict__ gamma,
    const float* __restrict__ beta, u16* __restrict__ xnT) {
  __shared__ u16 tile[64][72];
  int b = blockIdx.z;
  int c0 = blockIdx.y * 64, n0 = blockIdx.x * 64;
  int t = threadIdx.x;
  int cl = t >> 2, ng = (t & 3) * 16;
  int c = c0 + cl;
  float mean = stats[(b * 32 + (c >> 4)) * 2];
  float rstd = stats[(b * 32 + (c >> 4)) * 2 + 1];
  float a = gamma[c] * rstd;
  float b2 = beta[c] - mean * a;
  const float* src = x + ((size_t)b * 512 + c) * 4096 + n0 + ng;
  u16 e[16];
  #pragma unroll
  for (int q = 0; q < 4; ++q) {
    float4 v = *(const float4*)(src + q * 4);
    e[q * 4 + 0] = f2bf(v.x * a + b2);
    e[q * 4 + 1] = f2bf(v.y * a + b2);
    e[q * 4 + 2] = f2bf(v.z * a + b2);
    e[q * 4 + 3] = f2bf(v.w * a + b2);
  }
  #pragma unroll
  for (int j = 0; j < 16; ++j) tile[ng + j][cl] = e[j];
  __syncthreads();
  int nl = t >> 2, cg = (t & 3) * 16;
  uint4 w0 = *(const uint4*)&tile[nl][cg];
  uint4 w1 = *(const uint4*)&tile[nl][cg + 8];
  u16* dst = xnT + ((size_t)b * 4096 + n0 + nl) * 512 + c0 + cg;
  *(uint4*)dst = w0;
  *(uint4*)(dst + 8) = w1;
}

// ---------------- unified NT GEMM: C[m][n] = sum_k A[m*lda+k]*B[n*ldb+k] ----
// 128x128 tile, BK=32, global_load_lds, 4 waves * 4x4 accs.
// EPI: 1 = fp32 out plain (S, PV-partial)
//      3 = fp32 out + bias[m] + resid (proj)
//      4 = bf16 out, (acc+bias[n])*scale  (qk, n = output-channel)
//      5 = bf16 out, acc+bias[m]          (v)
template<int EPI>
__global__ __launch_bounds__(256) void gemm_nt(
    const u16* __restrict__ A, const u16* __restrict__ B,
    int lda, int ldb, int K,
    const float* __restrict__ bias, const float* __restrict__ resid,
    float scale, float* __restrict__ outF, u16* __restrict__ outB, int ldo,
    size_t azs, size_t bzs, size_t ozs) {
  __shared__ __align__(16) u16 Al[128 * 32];
  __shared__ __align__(16) u16 Bl[128 * 32];
  const size_t z = blockIdx.z;
  A += z * azs; B += z * bzs;
  const int t = threadIdx.x;
  const int wave = t >> 6, lane = t & 63;
  const int wm = wave >> 1, wn = wave & 1;
  const int quad = lane >> 4, li = lane & 15;
  const int m0 = blockIdx.y * 128, n0 = blockIdx.x * 128;

  const int srow = lane >> 2;
  const int scol = (lane & 3) * 8;
  const u16* gA[2];
  const u16* gB[2];
  u16* lA[2];
  u16* lB[2];
  #pragma unroll
  for (int r = 0; r < 2; ++r) {
    int rb = wave + 4 * r;
    gA[r] = A + (size_t)(m0 + rb * 16 + srow) * lda + scol;
    gB[r] = B + (size_t)(n0 + rb * 16 + srow) * ldb + scol;
    lA[r] = &Al[rb * 512];
    lB[r] = &Bl[rb * 512];
  }

  f32x4 zero = {0.f, 0.f, 0.f, 0.f};
  f32x4 acc[4][4];
  #pragma unroll
  for (int i = 0; i < 4; ++i)
    #pragma unroll
    for (int j = 0; j < 4; ++j) acc[i][j] = zero;

  for (int kt = 0; kt < K; kt += 32) {
    __syncthreads();
    #pragma unroll
    for (int r = 0; r < 2; ++r) {
      gld_lds16(gA[r] + kt, lA[r]);
      gld_lds16(gB[r] + kt, lB[r]);
    }
    __syncthreads();
    bf16x8 af[4], bf[4];
    #pragma unroll
    for (int i = 0; i < 4; ++i) {
      af[i] = *(const bf16x8*)&Al[(wm * 64 + i * 16 + li) * 32 + quad * 8];
      bf[i] = *(const bf16x8*)&Bl[(wn * 64 + i * 16 + li) * 32 + quad * 8];
    }
    #pragma unroll
    for (int i = 0; i < 4; ++i)
      #pragma unroll
      for (int j = 0; j < 4; ++j)
        acc[i][j] = __builtin_amdgcn_mfma_f32_16x16x32_bf16(
            af[i], bf[j], acc[i][j], 0, 0, 0);
  }

  if (EPI == 1 || EPI == 3) outF += z * ozs;
  if (EPI == 4 || EPI == 5) outB += z * ozs;

  #pragma unroll
  for (int i = 0; i < 4; ++i)
    #pragma unroll
    for (int j = 0; j < 4; ++j) {
      int mB = m0 + wm * 64 + i * 16 + quad * 4;
      int n = n0 + wn * 64 + j * 16 + li;
      #pragma unroll
      for (int r = 0; r < 4; ++r) {
        int m = mB + r;
        float v = acc[i][j][r];
        if (EPI == 1) {
          outF[(size_t)m * ldo + n] = v;
        } else if (EPI == 3) {
          v += bias[m] + resid[(size_t)m * ldo + n];
          outF[(size_t)m * ldo + n] = v;
        } else if (EPI == 4) {
          outB[(size_t)m * ldo + n] = f2bf((v + bias[n]) * scale);
        } else {
          outB[(size_t)m * ldo + n] = f2bf(v + bias[m]);
        }
      }
    }
}

// ---------------- row softmax (4096 fp32 -> 4096 bf16) ----------------
__global__ __launch_bounds__(256) void softmax_rows(const float* __restrict__ S,
                                                    u16* __restrict__ P) {
  int row = blockIdx.x;
  const float4* src = (const float4*)(S + (size_t)row * 4096);
  int t = threadIdx.x;
  float4 v[4];
  float m = -3.4e38f;
  #pragma unroll
  for (int i = 0; i < 4; ++i) {
    v[i] = src[t + i * 256];
    m = fmaxf(m, fmaxf(fmaxf(v[i].x, v[i].y), fmaxf(v[i].z, v[i].w)));
  }
  int lane = t & 63, w = t >> 6;
  for (int off = 32; off; off >>= 1) m = fmaxf(m, __shfl_down(m, off));
  __shared__ float red[4];
  if (lane == 0) red[w] = m;
  __syncthreads();
  m = fmaxf(fmaxf(red[0], red[1]), fmaxf(red[2], red[3]));
  __syncthreads();
  float s = 0.f;
  #pragma unroll
  for (int i = 0; i < 4; ++i) {
    v[i].x = __expf(v[i].x - m); v[i].y = __expf(v[i].y - m);
    v[i].z = __expf(v[i].z - m); v[i].w = __expf(v[i].w - m);
    s += v[i].x + v[i].y + v[i].z + v[i].w;
  }
  for (int off = 32; off; off >>= 1) s += __shfl_down(s, off);
  if (lane == 0) red[w] = s;
  __syncthreads();
  s = red[0] + red[1] + red[2] + red[3];
  float inv = 1.f / s;
  ushort4* dst = (ushort4*)(P + (size_t)row * 4096);
  #pragma unroll
  for (int i = 0; i < 4; ++i) {
    ushort4 o;
    o.x = f2bf(v[i].x * inv); o.y = f2bf(v[i].y * inv);
    o.z = f2bf(v[i].z * inv); o.w = f2bf(v[i].w * inv);
    dst[t + i * 256] = o;
  }
}

// ---------------- PV split-K reduce: ao = bf16(sum_z part[z]) ----------------
__global__ __launch_bounds__(256) void pv_reduce(const float* __restrict__ part,
                                                 u16* __restrict__ ao) {
  size_t i = ((size_t)blockIdx.x * 256 + threadIdx.x) * 4;
  float4 s = *(const float4*)(part + i);
  #pragma unroll
  for (int zz = 1; zz < 4; ++zz) {
    float4 p = *(const float4*)(part + (size_t)zz * 2097152 + i);
    s.x += p.x; s.y += p.y; s.z += p.z; s.w += p.w;
  }
  ushort4 o;
  o.x = f2bf(s.x); o.y = f2bf(s.y); o.z = f2bf(s.z); o.w = f2bf(s.w);
  *(ushort4*)(ao + i) = o;
}

extern "C" void kernel_launch(void* const* d_in, const int* in_sizes, int n_in,
                              void* d_out, int out_size, void* d_ws, size_t ws_size,
                              hipStream_t stream) {
  (void)in_sizes; (void)n_in; (void)out_size; (void)ws_size;
  const float* x      = (const float*)d_in[0];
  const float* gamma  = (const float*)d_in[1];
  const float* beta   = (const float*)d_in[2];
  const float* w_qkv  = (const float*)d_in[3];
  const float* b_qkv  = (const float*)d_in[4];
  const float* w_proj = (const float*)d_in[5];
  const float* b_proj = (const float*)d_in[6];
  float* out = (float*)d_out;

  const int C = 512, N = 4096;
  const float scale = 0.21022410381342863f;  // 512^-0.25

  char* ws = (char*)d_ws;
  size_t off = 0;
  auto alloc = [&](size_t bytes) -> char* {
    char* p = ws + off; off += (bytes + 255) & ~(size_t)255; return p;
  };
  u16*   wq_bf = (u16*)alloc((size_t)1536 * 512 * 2);
  u16*   wp_bf = (u16*)alloc((size_t)512 * 512 * 2);
  float* stats = (float*)alloc(128 * 2 * 4);
  u16*   xnT   = (u16*)alloc((size_t)4 * N * C * 2);  // [b][n][c]
  u16*   qkT   = (u16*)alloc((size_t)N * 1024 * 2);   // per-batch [i][o], o<1024
  u16*   vbf   = (u16*)alloc((size_t)C * N * 2);      // per-batch v[c][j]
  float* S     = (float*)alloc((size_t)N * N * 4);    // per-batch; pvpart aliases
  u16*   P     = (u16*)alloc((size_t)N * N * 2);      // per-batch
  u16*   ao    = (u16*)alloc((size_t)N * C * 2);      // per-batch O[i][c]
  float* pvpart = S;  // [4][4096][512] fp32 = 32 MB, S dead after softmax

  cvt_weights<<<3072, 256, 0, stream>>>(w_qkv, w_proj, wq_bf, wp_bf);
  gn_stats<<<128, 256, 0, stream>>>(x, stats);
  gn_norm_t<<<dim3(64, 8, 4), 256, 0, stream>>>(x, stats, gamma, beta, xnT);

  for (int b = 0; b < 4; ++b) {
    const u16* xbT = xnT + (size_t)b * N * C;
    const float* xres = x + (size_t)b * C * N;
    // qkT[i][o] = (sum_c xnT[i][c]*wq[o][c] + b_qkv[o]) * scale, o in [0,1024)
    gemm_nt<4><<<dim3(8, 32), 256, 0, stream>>>(
        xbT, wq_bf, 512, 512, 512, b_qkv, nullptr, scale,
        nullptr, qkT, 1024, 0, 0, 0);
    // v[c][j] = sum_k wq[1024+c][k]*xnT[j][k] + b_qkv[1024+c]
    gemm_nt<5><<<dim3(32, 4), 256, 0, stream>>>(
        wq_bf + (size_t)1024 * 512, xbT, 512, 512, 512, b_qkv + 1024, nullptr,
        0.f, nullptr, vbf, 4096, 0, 0, 0);
    // S[i][j] = sum_c qkT[i][c]*qkT[j][512+c]
    gemm_nt<1><<<dim3(32, 32), 256, 0, stream>>>(
        qkT, qkT + 512, 1024, 1024, 512, nullptr, nullptr, 0.f,
        S, nullptr, 4096, 0, 0, 0);
    softmax_rows<<<4096, 256, 0, stream>>>(S, P);
    // pvpart[z][i][c] = sum_{j in seg z} P[i][j]*v[c][j]
    gemm_nt<1><<<dim3(4, 32, 4), 256, 0, stream>>>(
        P, vbf, 4096, 4096, 1024, nullptr, nullptr, 0.f,
        pvpart, nullptr, 512, 1024, 1024, (size_t)N * 512);
    pv_reduce<<<2048, 256, 0, stream>>>(pvpart, ao);
    // out[o][n] = sum_c wp[o][c]*ao[n][c] + b_proj[o] + x[o][n]
    gemm_nt<3><<<dim3(32, 4), 256, 0, stream>>>(
        wp_bf, ao, 512, 512, 512, b_proj, xres, 0.f,
        out + (size_t)b * C * N, nullptr, 4096, 0, 0, 0);
  }
}

// Round 4
// 530.923 us; speedup vs baseline: 2.1476x; 1.2666x over previous
//
#include <hip/hip_runtime.h>
#include <stdint.h>

typedef unsigned short u16;
typedef __bf16 bf16x8 __attribute__((ext_vector_type(8)));
typedef float f32x4 __attribute__((ext_vector_type(4)));

__device__ __forceinline__ u16 f2bf(float f) {
  union { float f; unsigned u; } v; v.f = f;
  return (u16)((v.u + 0x7FFFu + ((v.u >> 16) & 1u)) >> 16);
}
__device__ __forceinline__ float bf2f(u16 h) {
  union { unsigned u; float f; } v; v.u = ((unsigned)h) << 16; return v.f;
}

// async 16B global -> LDS (wave-uniform LDS base; HW writes base + lane*16)
__device__ __forceinline__ void gld_lds16(const u16* g, u16* l) {
  uint32_t lo = (uint32_t)(uintptr_t)l;
  lo = __builtin_amdgcn_readfirstlane(lo);
  auto* lp = (__attribute__((address_space(3))) uint32_t*)(uintptr_t)lo;
  auto* gp = (const __attribute__((address_space(1))) uint32_t*)(uintptr_t)g;
  __builtin_amdgcn_global_load_lds(gp, lp, 16, 0, 0);
}

// ---------------- weight fp32 -> bf16 ----------------
__global__ __launch_bounds__(256) void cvt_weights(
    const float* __restrict__ wq, const float* __restrict__ wp,
    u16* __restrict__ oq, u16* __restrict__ op) {
  int i = blockIdx.x * 256 + threadIdx.x;
  if (i < 1536 * 512) oq[i] = f2bf(wq[i]);
  if (i < 512 * 512)  op[i] = f2bf(wp[i]);
}

// ---------------- group norm stats ----------------
__global__ __launch_bounds__(256) void gn_stats(const float* __restrict__ x,
                                                float* __restrict__ stats) {
  int bg = blockIdx.x;  // 0..127
  const float* p = x + (size_t)bg * 65536;
  float s = 0.f, sq = 0.f;
  for (int i = threadIdx.x * 4; i < 65536; i += 1024) {
    float4 v = *(const float4*)(p + i);
    s += v.x + v.y + v.z + v.w;
    sq += v.x * v.x + v.y * v.y + v.z * v.z + v.w * v.w;
  }
  int lane = threadIdx.x & 63, w = threadIdx.x >> 6;
  for (int off = 32; off; off >>= 1) {
    s += __shfl_down(s, off);
    sq += __shfl_down(sq, off);
  }
  __shared__ float ls[4], lq[4];
  if (lane == 0) { ls[w] = s; lq[w] = sq; }
  __syncthreads();
  if (threadIdx.x == 0) {
    float S = ls[0] + ls[1] + ls[2] + ls[3];
    float Q = lq[0] + lq[1] + lq[2] + lq[3];
    float mean = S * (1.f / 65536.f);
    float var = Q * (1.f / 65536.f) - mean * mean;
    stats[bg * 2] = mean;
    stats[bg * 2 + 1] = rsqrtf(var + 1e-6f);
  }
}

// ---------------- group norm + transpose: x[b][c][n] -> xnT[b][n][c] bf16 ----
__global__ __launch_bounds__(256) void gn_norm_t(const float* __restrict__ x,
    const float* __restrict__ stats, const float* __restrict__ gamma,
    const float* __restrict__ beta, u16* __restrict__ xnT) {
  __shared__ u16 tile[64][72];
  int b = blockIdx.z;
  int c0 = blockIdx.y * 64, n0 = blockIdx.x * 64;
  int t = threadIdx.x;
  int cl = t >> 2, ng = (t & 3) * 16;
  int c = c0 + cl;
  float mean = stats[(b * 32 + (c >> 4)) * 2];
  float rstd = stats[(b * 32 + (c >> 4)) * 2 + 1];
  float a = gamma[c] * rstd;
  float b2 = beta[c] - mean * a;
  const float* src = x + ((size_t)b * 512 + c) * 4096 + n0 + ng;
  u16 e[16];
  #pragma unroll
  for (int q = 0; q < 4; ++q) {
    float4 v = *(const float4*)(src + q * 4);
    e[q * 4 + 0] = f2bf(v.x * a + b2);
    e[q * 4 + 1] = f2bf(v.y * a + b2);
    e[q * 4 + 2] = f2bf(v.z * a + b2);
    e[q * 4 + 3] = f2bf(v.w * a + b2);
  }
  #pragma unroll
  for (int j = 0; j < 16; ++j) tile[ng + j][cl] = e[j];
  __syncthreads();
  int nl = t >> 2, cg = (t & 3) * 16;
  uint4 w0 = *(const uint4*)&tile[nl][cg];
  uint4 w1 = *(const uint4*)&tile[nl][cg + 8];
  u16* dst = xnT + ((size_t)b * 4096 + n0 + nl) * 512 + c0 + cg;
  *(uint4*)dst = w0;
  *(uint4*)(dst + 8) = w1;
}

// ---------------- unified NT GEMM: C[m][n] = sum_k A[m*lda+k]*B[n*ldb+k] ----
// 128x128 tile, BK=32, global_load_lds, 4 waves * 4x4 accs. z strides A/B/out.
// EPI: 2 = bf16 out plain (PV partial)
//      3 = fp32 out + bias[m] + resid (proj; resid/out strided by z*ozs)
//      4 = bf16 out, (acc+bias[n])*scale  (qk: m=spatial, n=channel)
//      5 = bf16 out, acc+bias[m]          (v:  m=channel, n=spatial)
//      7 = bf16 out exp(acc), atomicAdd row-sums into outF[m]
template<int EPI>
__global__ __launch_bounds__(256) void gemm_nt(
    const u16* __restrict__ A, const u16* __restrict__ B,
    int lda, int ldb, int K,
    const float* __restrict__ bias, const float* __restrict__ resid,
    float scale, float* __restrict__ outF, u16* __restrict__ outB, int ldo,
    size_t azs, size_t bzs, size_t ozs) {
  __shared__ __align__(16) u16 Al[128 * 32];
  __shared__ __align__(16) u16 Bl[128 * 32];
  const size_t z = blockIdx.z;
  A += z * azs; B += z * bzs;
  const int t = threadIdx.x;
  const int wave = t >> 6, lane = t & 63;
  const int wm = wave >> 1, wn = wave & 1;
  const int quad = lane >> 4, li = lane & 15;
  const int m0 = blockIdx.y * 128, n0 = blockIdx.x * 128;

  const int srow = lane >> 2;
  const int scol = (lane & 3) * 8;
  const u16* gA[2];
  const u16* gB[2];
  u16* lA[2];
  u16* lB[2];
  #pragma unroll
  for (int r = 0; r < 2; ++r) {
    int rb = wave + 4 * r;
    gA[r] = A + (size_t)(m0 + rb * 16 + srow) * lda + scol;
    gB[r] = B + (size_t)(n0 + rb * 16 + srow) * ldb + scol;
    lA[r] = &Al[rb * 512];
    lB[r] = &Bl[rb * 512];
  }

  f32x4 zero = {0.f, 0.f, 0.f, 0.f};
  f32x4 acc[4][4];
  #pragma unroll
  for (int i = 0; i < 4; ++i)
    #pragma unroll
    for (int j = 0; j < 4; ++j) acc[i][j] = zero;

  for (int kt = 0; kt < K; kt += 32) {
    __syncthreads();
    #pragma unroll
    for (int r = 0; r < 2; ++r) {
      gld_lds16(gA[r] + kt, lA[r]);
      gld_lds16(gB[r] + kt, lB[r]);
    }
    __syncthreads();
    bf16x8 af[4], bf[4];
    #pragma unroll
    for (int i = 0; i < 4; ++i) {
      af[i] = *(const bf16x8*)&Al[(wm * 64 + i * 16 + li) * 32 + quad * 8];
      bf[i] = *(const bf16x8*)&Bl[(wn * 64 + i * 16 + li) * 32 + quad * 8];
    }
    #pragma unroll
    for (int i = 0; i < 4; ++i)
      #pragma unroll
      for (int j = 0; j < 4; ++j)
        acc[i][j] = __builtin_amdgcn_mfma_f32_16x16x32_bf16(
            af[i], bf[j], acc[i][j], 0, 0, 0);
  }

  if (EPI == 3) { outF += z * ozs; resid += z * ozs; }
  if (EPI == 2 || EPI == 4 || EPI == 5) outB += z * ozs;

  #pragma unroll
  for (int i = 0; i < 4; ++i) {
    float rs[4] = {0.f, 0.f, 0.f, 0.f};
    #pragma unroll
    for (int j = 0; j < 4; ++j) {
      int mB = m0 + wm * 64 + i * 16 + quad * 4;
      int n = n0 + wn * 64 + j * 16 + li;
      #pragma unroll
      for (int r = 0; r < 4; ++r) {
        int m = mB + r;
        float v = acc[i][j][r];
        if (EPI == 2) {
          outB[(size_t)m * ldo + n] = f2bf(v);
        } else if (EPI == 3) {
          v += bias[m] + resid[(size_t)m * ldo + n];
          outF[(size_t)m * ldo + n] = v;
        } else if (EPI == 4) {
          outB[(size_t)m * ldo + n] = f2bf((v + bias[n]) * scale);
        } else if (EPI == 5) {
          outB[(size_t)m * ldo + n] = f2bf(v + bias[m]);
        } else {  // EPI 7
          float e = __expf(v);
          outB[(size_t)m * ldo + n] = f2bf(e);
          rs[r] += e;
        }
      }
    }
    if (EPI == 7) {
      #pragma unroll
      for (int r = 0; r < 4; ++r) {
        rs[r] += __shfl_xor(rs[r], 1);
        rs[r] += __shfl_xor(rs[r], 2);
        rs[r] += __shfl_xor(rs[r], 4);
        rs[r] += __shfl_xor(rs[r], 8);
      }
      if (li == 0) {
        int mB = m0 + wm * 64 + i * 16 + quad * 4;
        #pragma unroll
        for (int r = 0; r < 4; ++r) atomicAdd(&outF[mB + r], rs[r]);
      }
    }
  }
}

// -------- PV split-K reduce: ao = bf16((sum_z part[z]) / rowsum) ----------
__global__ __launch_bounds__(256) void pv_reduce(const u16* __restrict__ part,
    const float* __restrict__ rowsum, u16* __restrict__ ao) {
  size_t i = ((size_t)blockIdx.x * 256 + threadIdx.x) * 4;
  int row = (int)(i >> 9);
  float inv = __builtin_amdgcn_rcpf(rowsum[row]);
  float s0 = 0.f, s1 = 0.f, s2 = 0.f, s3 = 0.f;
  #pragma unroll
  for (int zz = 0; zz < 4; ++zz) {
    ushort4 p = *(const ushort4*)(part + (size_t)zz * 2097152 + i);
    s0 += bf2f(p.x); s1 += bf2f(p.y); s2 += bf2f(p.z); s3 += bf2f(p.w);
  }
  ushort4 o;
  o.x = f2bf(s0 * inv); o.y = f2bf(s1 * inv);
  o.z = f2bf(s2 * inv); o.w = f2bf(s3 * inv);
  *(ushort4*)(ao + i) = o;
}

extern "C" void kernel_launch(void* const* d_in, const int* in_sizes, int n_in,
                              void* d_out, int out_size, void* d_ws, size_t ws_size,
                              hipStream_t stream) {
  (void)in_sizes; (void)n_in; (void)out_size; (void)ws_size;
  const float* x      = (const float*)d_in[0];
  const float* gamma  = (const float*)d_in[1];
  const float* beta   = (const float*)d_in[2];
  const float* w_qkv  = (const float*)d_in[3];
  const float* b_qkv  = (const float*)d_in[4];
  const float* w_proj = (const float*)d_in[5];
  const float* b_proj = (const float*)d_in[6];
  float* out = (float*)d_out;

  const int C = 512, N = 4096;
  const size_t NC = (size_t)N * C;
  const float scale = 0.21022410381342863f;  // 512^-0.25

  char* ws = (char*)d_ws;
  size_t off = 0;
  auto alloc = [&](size_t bytes) -> char* {
    char* p = ws + off; off += (bytes + 255) & ~(size_t)255; return p;
  };
  u16*   wq_bf  = (u16*)alloc((size_t)1536 * 512 * 2);
  u16*   wp_bf  = (u16*)alloc((size_t)512 * 512 * 2);
  float* stats  = (float*)alloc(128 * 2 * 4);
  float* rowsum = (float*)alloc((size_t)4 * N * 4);
  u16*   xnT    = (u16*)alloc((size_t)4 * NC * 2);        // [b][n][c]
  u16*   qkT    = (u16*)alloc((size_t)4 * N * 1024 * 2);  // [b][i][o], o<1024
  u16*   vbf    = (u16*)alloc((size_t)4 * NC * 2);        // [b][c][j]
  u16*   ao     = (u16*)alloc((size_t)4 * NC * 2);        // [b][i][c]
  u16*   E      = (u16*)alloc((size_t)N * N * 2);         // per-batch exp(S)
  u16*   pvpart = (u16*)alloc((size_t)4 * NC * 2);        // per-batch [z][i][c]

  cvt_weights<<<3072, 256, 0, stream>>>(w_qkv, w_proj, wq_bf, wp_bf);
  gn_stats<<<128, 256, 0, stream>>>(x, stats);
  gn_norm_t<<<dim3(64, 8, 4), 256, 0, stream>>>(x, stats, gamma, beta, xnT);
  hipMemsetAsync(rowsum, 0, (size_t)4 * N * 4, stream);

  // qkT[b][i][o] = (sum_c xnT[b][i][c]*wq[o][c] + b_qkv[o]) * scale
  gemm_nt<4><<<dim3(8, 32, 4), 256, 0, stream>>>(
      xnT, wq_bf, 512, 512, 512, b_qkv, nullptr, scale,
      nullptr, qkT, 1024, NC, 0, (size_t)N * 1024);
  // vbf[b][c][j] = sum_k wq[1024+c][k]*xnT[b][j][k] + b_qkv[1024+c]
  gemm_nt<5><<<dim3(32, 4, 4), 256, 0, stream>>>(
      wq_bf + (size_t)1024 * 512, xnT, 512, 512, 512, b_qkv + 1024, nullptr,
      0.f, nullptr, vbf, 4096, 0, NC, NC);

  for (int b = 0; b < 4; ++b) {
    const u16* qkb = qkT + (size_t)b * N * 1024;
    // E[i][j] = bf16(exp(S[i][j])), rowsum[b][i] += partials
    gemm_nt<7><<<dim3(32, 32), 256, 0, stream>>>(
        qkb, qkb + 512, 1024, 1024, 512, nullptr, nullptr, 0.f,
        rowsum + (size_t)b * N, E, 4096, 0, 0, 0);
    // pvpart[z][i][c] = sum_{j in seg z} E[i][j]*v[c][j]   (bf16)
    gemm_nt<2><<<dim3(4, 32, 4), 256, 0, stream>>>(
        E, vbf + (size_t)b * NC, 4096, 4096, 1024, nullptr, nullptr, 0.f,
        nullptr, pvpart, 512, 1024, 1024, NC);
    // ao[b][i][c] = bf16(sum_z pvpart / rowsum[b][i])
    pv_reduce<<<2048, 256, 0, stream>>>(pvpart, rowsum + (size_t)b * N,
                                        ao + (size_t)b * NC);
  }

  // out[b][o][n] = sum_c wp[o][c]*ao[b][n][c] + b_proj[o] + x[b][o][n]
  gemm_nt<3><<<dim3(32, 4, 4), 256, 0, stream>>>(
      wp_bf, ao, 512, 512, 512, b_proj, x, 0.f,
      out, nullptr, 4096, 0, NC, NC);
}